// Round 10
// baseline (346.369 us; speedup 1.0000x reference)
//
#include <hip/hip_runtime.h>
#include <hip/hip_bf16.h>

constexpr int kNN  = 10000;   // nodes
constexpr int kTT  = 12;      // timesteps
constexpr int kFIN = 32;      // input features
constexpr int kHH  = 64;      // hidden
constexpr int kH4  = 256;     // 4*hidden (gates)
constexpr int kOUT = 16;      // output features
constexpr int kNE  = 160000;  // edges

typedef _Float16 half8 __attribute__((ext_vector_type(8)));
typedef _Float16 half4 __attribute__((ext_vector_type(4)));
typedef _Float16 half2t __attribute__((ext_vector_type(2)));
typedef float floatx4 __attribute__((ext_vector_type(4)));

__device__ __forceinline__ float sigf(float x){ return 1.f/(1.f+__expf(-x)); }
__device__ __forceinline__ float tanh_fast(float x){
  float xc = fminf(fmaxf(x,-30.f),30.f);
  float e = __expf(-2.f*xc);
  return (1.f-e)/(1.f+e);
}

// int64-vs-int32 edge_index detection (odd words all zero <=> int64) fused
// with the x fp32 -> fp16 cast.
__global__ void k_detect_cast(const int* __restrict__ ei, int* __restrict__ anyf,
                              const float* __restrict__ x, _Float16* __restrict__ xh){
  int a = 0;
  for (int i = blockIdx.x*256 + threadIdx.x; i < kNE; i += gridDim.x*256)
    a |= ei[2*i+1];
  unsigned long long m = __ballot(a != 0);
  if ((threadIdx.x & 63) == 0 && m) atomicOr(anyf, 1);
  const int NV = kNN*kTT*kFIN/4;
  for (int i = blockIdx.x*256 + threadIdx.x; i < NV; i += gridDim.x*256){
    float4 v = *(const float4*)&x[4*i];
    half4 h;
    h[0]=(_Float16)v.x; h[1]=(_Float16)v.y; h[2]=(_Float16)v.z; h[3]=(_Float16)v.w;
    *(half4*)&xh[4*i] = h;
  }
}

__global__ void k_deg(const int* __restrict__ ei, const int* __restrict__ anyf,
                      int* __restrict__ cnt){
  int e = blockIdx.x*256 + threadIdx.x;
  if (e >= kNE) return;
  int c = (anyf[0]==0) ? ei[2*(kNE+e)] : ei[kNE+e];
  atomicAdd(&cnt[c], 1);
}

// Exclusive scan of in-degree (single block) + dis = rsqrt(deg+selfloop)
__global__ void k_scan(const int* __restrict__ cnt, int* __restrict__ offs,
                       float* __restrict__ dis){
  __shared__ int wsum[4];
  int tid = threadIdx.x;
  const int CH = (kNN + 255)/256;
  int lo = tid*CH, hi = min(lo+CH, kNN);
  int s = 0;
  for (int i = lo; i < hi; ++i) s += cnt[i];
  int orig = s;
  int lane = tid & 63, wv = tid >> 6;
  #pragma unroll
  for (int d = 1; d < 64; d <<= 1){
    int v = __shfl_up(s, d, 64);
    if (lane >= d) s += v;
  }
  if (lane == 63) wsum[wv] = s;
  __syncthreads();
  int add = 0;
  for (int k2 = 0; k2 < wv; ++k2) add += wsum[k2];
  int run = s - orig + add;
  for (int i = lo; i < hi; ++i){ offs[i] = run; run += cnt[i]; }
  if (hi == kNN) offs[kNN] = run;
  for (int i = tid; i < kNN; i += 256) dis[i] = rsqrtf((float)(cnt[i]+1));
}

// CSR scatter; packs (src, weight) into one int2 per edge.
__global__ void k_scatter(const int* __restrict__ ei, const int* __restrict__ anyf,
                          const int* __restrict__ offs, int* __restrict__ cur,
                          const float* __restrict__ dis,
                          int2* __restrict__ edat){
  int e = blockIdx.x*256 + threadIdx.x;
  if (e >= kNE) return;
  int f = (anyf[0]==0);
  int r = f ? ei[2*e]         : ei[e];
  int c = f ? ei[2*(kNE+e)]   : ei[kNE+e];
  int p = offs[c] + atomicAdd(&cur[c], 1);
  edat[p] = make_int2(r, __float_as_int(dis[r]*dis[c]));
}

// Pure GCN aggregation (bias/relu folded into the following GEMM).
template<int F>
__global__ __launch_bounds__(256) void k_agg(const _Float16* __restrict__ hin,
                     _Float16* __restrict__ hout,
                     const float* __restrict__ dis,
                     const int* __restrict__ offs, const int2* __restrict__ edat){
  constexpr int LPF = F/2;
  constexpr int TPW = 64/LPF;
  int wid = threadIdx.x >> 6, lane = threadIdx.x & 63;
  int gw = blockIdx.x*4 + wid;
  int tq = gw / kNN, n = gw - tq*kNN;
  int fp = lane & (LPF-1), tsub = lane / LPF;
  int t = TPW*tq + tsub;
  const _Float16* hb = hin + (size_t)t*kNN*F;
  float d = dis[n], ws = d*d;
  half2t sv = *(const half2t*)&hb[(size_t)n*F + 2*fp];
  float a0 = ws*(float)sv[0], a1 = ws*(float)sv[1];
  int e0 = __builtin_amdgcn_readfirstlane(offs[n]);
  int e1 = __builtin_amdgcn_readfirstlane(offs[n+1]);
  int e = e0;
  for (; e + 8 <= e1; e += 8){
    int2 d8[8];
    #pragma unroll
    for (int u = 0; u < 8; ++u) d8[u] = edat[e+u];
    half2t v[8];
    #pragma unroll
    for (int u = 0; u < 8; ++u) v[u] = *(const half2t*)&hb[(size_t)d8[u].x*F + 2*fp];
    #pragma unroll
    for (int u = 0; u < 8; ++u){
      float wu = __int_as_float(d8[u].y);
      a0 = fmaf(wu, (float)v[u][0], a0);
      a1 = fmaf(wu, (float)v[u][1], a1);
    }
  }
  for (; e < e1; ++e){
    int2 du = edat[e];
    float wu = __int_as_float(du.y);
    half2t vu = *(const half2t*)&hb[(size_t)du.x*F + 2*fp];
    a0 = fmaf(wu, (float)vu[0], a0);
    a1 = fmaf(wu, (float)vu[1], a1);
  }
  half2t o; o[0] = (_Float16)a0; o[1] = (_Float16)a1;
  *(half2t*)&hout[((size_t)t*kNN + n)*F + 2*fp] = o;
}

// Tiled GEMM: out[M,N] = relu(in[M,K] @ W[K,N] + bias), fp16 in/out, fp32 acc.
template<int K, int N, bool NM>
__global__ __launch_bounds__(256) void k_gemm(const _Float16* __restrict__ in,
                      const float* __restrict__ Wg, const float* __restrict__ bias,
                      _Float16* __restrict__ out){
  constexpr int COLG = N/4;
  constexpr int ROWG = 256/COLG;
  constexpr int MR   = 4;
  constexpr int MTILE= ROWG*MR;
  constexpr int AP   = K + 4;
  __shared__ float Wl[K*N];
  __shared__ float Al[MTILE*AP];
  int tid = threadIdx.x;
  int m0 = blockIdx.x*MTILE;
  for (int idx = tid; idx < MTILE*K/8; idx += 256){
    int r = idx/(K/8), k8 = idx - r*(K/8);
    half8 v = *(const half8*)&in[(size_t)(m0 + r)*K + k8*8];
    float* dst = &Al[r*AP + k8*8];
    #pragma unroll
    for (int j = 0; j < 8; ++j) dst[j] = (float)v[j];
  }
  for (int idx = tid; idx < K*N; idx += 256) Wl[idx] = Wg[idx];
  __syncthreads();
  int cg = tid % COLG, rg = tid / COLG;
  int c0 = cg*4, r0 = rg*MR;
  float acc[MR][4];
  #pragma unroll
  for (int r=0;r<MR;++r){acc[r][0]=0.f;acc[r][1]=0.f;acc[r][2]=0.f;acc[r][3]=0.f;}
  #pragma unroll 2
  for (int k = 0; k < K; k += 4){
    float4 wv[4];
    #pragma unroll
    for (int kk = 0; kk < 4; ++kk) wv[kk] = *(const float4*)&Wl[(k+kk)*N + c0];
    #pragma unroll
    for (int r = 0; r < MR; ++r){
      float4 a4 = *(const float4*)&Al[(r0+r)*AP + k];
      acc[r][0] = fmaf(a4.x, wv[0].x, acc[r][0]);
      acc[r][1] = fmaf(a4.x, wv[0].y, acc[r][1]);
      acc[r][2] = fmaf(a4.x, wv[0].z, acc[r][2]);
      acc[r][3] = fmaf(a4.x, wv[0].w, acc[r][3]);
      acc[r][0] = fmaf(a4.y, wv[1].x, acc[r][0]);
      acc[r][1] = fmaf(a4.y, wv[1].y, acc[r][1]);
      acc[r][2] = fmaf(a4.y, wv[1].z, acc[r][2]);
      acc[r][3] = fmaf(a4.y, wv[1].w, acc[r][3]);
      acc[r][0] = fmaf(a4.z, wv[2].x, acc[r][0]);
      acc[r][1] = fmaf(a4.z, wv[2].y, acc[r][1]);
      acc[r][2] = fmaf(a4.z, wv[2].z, acc[r][2]);
      acc[r][3] = fmaf(a4.z, wv[2].w, acc[r][3]);
      acc[r][0] = fmaf(a4.w, wv[3].x, acc[r][0]);
      acc[r][1] = fmaf(a4.w, wv[3].y, acc[r][1]);
      acc[r][2] = fmaf(a4.w, wv[3].z, acc[r][2]);
      acc[r][3] = fmaf(a4.w, wv[3].w, acc[r][3]);
    }
  }
  float4 bb = *(const float4*)&bias[c0];
  #pragma unroll
  for (int r = 0; r < MR; ++r){
    half4 hv;
    hv[0]=(_Float16)fmaxf(acc[r][0]+bb.x, 0.f);
    hv[1]=(_Float16)fmaxf(acc[r][1]+bb.y, 0.f);
    hv[2]=(_Float16)fmaxf(acc[r][2]+bb.z, 0.f);
    hv[3]=(_Float16)fmaxf(acc[r][3]+bb.w, 0.f);
    int m = m0 + r0 + r;
    size_t oi;
    if (NM){ int t = m/kNN, n = m - t*kNN; oi = ((size_t)n*kTT + t)*N + c0; }
    else    oi = (size_t)m*N + c0;
    *(half4*)&out[oi] = hv;
  }
}

// Stage a (256,64) fp32 matrix into LDS as fp16 MFMA B-fragments:
// frag fi=(g*2+kt): lane ln's half8 at dst[(fi*64+ln)*8] = W[g*16+(ln&15)]
// [kt*32+(ln>>4)*8 + j]  -> in-kernel read is one ds_read_b128 per frag.
__device__ __forceinline__ void stage_frags(const float* __restrict__ W,
                                            _Float16* __restrict__ dst,
                                            int tid, int nthr){
  for (int idx = tid; idx < 2048; idx += nthr){
    int fi = idx >> 6, ln = idx & 63;
    int g = fi >> 1, kt = fi & 1;
    const float* s = W + (size_t)(g*16 + (ln & 15))*kHH + kt*32 + ((ln >> 4) << 3);
    half8 v;
    #pragma unroll
    for (int j = 0; j < 8; ++j) v[j] = (_Float16)s[j];
    *(half8*)&dst[(size_t)idx*8] = v;
  }
}

// Barrier-free LSTM layer: ONE WAVE owns a 16-node tile end-to-end.
// Wih fragments live in 128 VGPRs; Whh fragments + bias in LDS; the 12-step
// recurrence has ZERO __syncthreads (h C->A transform via wave-private LDS
// scratch; same-wave DS ops are in-order).
// __launch_bounds__(128, 1): R9 post-mortem — with the default occupancy
// target the compiler capped at 144 VGPRs and SPILLED the 128-VGPR WihF
// array to scratch, reloading it every t at ~900cyc (66us/layer). We have
// only 625 waves for 1024 SIMDs, so occupancy can't bind — allow the full
// register budget instead (~200 VGPRs, no spill).
// MFMA 16x16x32 layouts: A[m=lane&15][k=(lane>>4)*8+j], B^T rows same,
// C/D[row=(lane>>4)*4+r][col=lane&15]. acc[q][r] = gate q of
// (node=quad*4+r, cell=gg*16+lo); bias broadcast per (q,cell) across r;
// h scratch store sc[(quad*4+r)*72 + gg*16+lo] (per-r b16 scatter).
// LAST: fuse FC on h(t=11) (2 MFMAs), write fp32 out; else write fp16 h-seq.
template<bool LAST>
__global__ __launch_bounds__(128, 1) void k_lstm(const _Float16* __restrict__ xin,
                     const float* __restrict__ wih, const float* __restrict__ whh,
                     const float* __restrict__ bih, const float* __restrict__ bhh,
                     const float* __restrict__ fcw, const float* __restrict__ fcb,
                     void* __restrict__ outp){
  __shared__ _Float16 WL[16384];     // 32KB Whh fragment image (Wih transient)
  __shared__ float    biasL[kH4];    // 1KB summed bias
  __shared__ _Float16 hs[2][1152];   // per-wave h scratch: [node*72 + cell]
  int tid = threadIdx.x, w = tid >> 6, lane = tid & 63;
  int lo = lane & 15, quad = lane >> 4;
  int tile = blockIdx.x*2 + w;
  int nb = tile*16;

  // --- one-time preload (the only barriers in the kernel) ---
  stage_frags(wih, WL, tid, 128);
  __syncthreads();
  half8 WihF[16][2];
  #pragma unroll
  for (int g = 0; g < 16; ++g){
    #pragma unroll
    for (int kt = 0; kt < 2; ++kt)
      WihF[g][kt] = *(const half8*)&WL[(size_t)((g*2+kt)*64 + lane)*8];
  }
  __syncthreads();
  stage_frags(whh, WL, tid, 128);
  for (int i = tid; i < kH4; i += 128) biasL[i] = bih[i] + bhh[i];
  __syncthreads();
  if (tile >= kNN/16) return;        // after all barriers

  // Per-lane bias: gate q, cell gg*16+lo (constant across the 4 node-rows r)
  float bias_v[4][4];
  #pragma unroll
  for (int gg = 0; gg < 4; ++gg)
    #pragma unroll
    for (int q = 0; q < 4; ++q)
      bias_v[gg][q] = biasL[q*64 + gg*16 + lo];

  half8 FW[2];
  if (LAST){
    #pragma unroll
    for (int kt = 0; kt < 2; ++kt){
      const float* pf = fcw + (size_t)lo*kHH + kt*32 + quad*8;
      half8 f;
      #pragma unroll
      for (int j = 0; j < 8; ++j) f[j] = (_Float16)pf[j];
      FW[kt] = f;
    }
  }

  const _Float16* xr = xin + (size_t)(nb + lo)*kTT*kHH;
  _Float16* sc = &hs[w][0];
  floatx4 cst[4];
  #pragma unroll
  for (int gg = 0; gg < 4; ++gg) cst[gg] = (floatx4){0.f,0.f,0.f,0.f};
  half8 ah0, ah1;
  half8 axn0 = *(const half8*)&xr[quad*8];
  half8 axn1 = *(const half8*)&xr[32 + quad*8];

  for (int t = 0; t < kTT; ++t){
    half8 ax0 = axn0, ax1 = axn1;
    if (t < kTT-1){
      axn0 = *(const half8*)&xr[(size_t)(t+1)*kHH + quad*8];
      axn1 = *(const half8*)&xr[(size_t)(t+1)*kHH + 32 + quad*8];
    }
    #pragma unroll
    for (int gg = 0; gg < 4; ++gg){
      floatx4 acc[4];
      #pragma unroll
      for (int q = 0; q < 4; ++q){
        float b = bias_v[gg][q];
        acc[q] = (floatx4){b, b, b, b};
      }
      #pragma unroll
      for (int q = 0; q < 4; ++q){
        int ga = q*4 + gg;
        acc[q] = __builtin_amdgcn_mfma_f32_16x16x32_f16(ax0, WihF[ga][0], acc[q], 0,0,0);
        acc[q] = __builtin_amdgcn_mfma_f32_16x16x32_f16(ax1, WihF[ga][1], acc[q], 0,0,0);
      }
      if (t > 0){
        #pragma unroll
        for (int q = 0; q < 4; ++q){
          int ga = q*4 + gg;
          half8 w0 = *(const half8*)&WL[(size_t)((ga*2+0)*64 + lane)*8];
          half8 w1 = *(const half8*)&WL[(size_t)((ga*2+1)*64 + lane)*8];
          acc[q] = __builtin_amdgcn_mfma_f32_16x16x32_f16(ah0, w0, acc[q], 0,0,0);
          acc[q] = __builtin_amdgcn_mfma_f32_16x16x32_f16(ah1, w1, acc[q], 0,0,0);
        }
      }
      #pragma unroll
      for (int r = 0; r < 4; ++r){
        float ii = sigf(acc[0][r]);
        float ff = sigf(acc[1][r]);
        float gt = tanh_fast(acc[2][r]);
        float oo = sigf(acc[3][r]);
        float cc = ff*cst[gg][r] + ii*gt;
        cst[gg][r] = cc;
        float hv = oo * tanh_fast(cc);
        // value is (node=quad*4+r, cell=gg*16+lo): scatter b16 per r
        sc[(quad*4 + r)*72 + gg*16 + lo] = (_Float16)hv;
      }
    }
    // h(t) C-layout -> A-layout for t+1 (and the FC at t=11). Same-wave DS
    // ops are in-order; compiler inserts the lgkmcnt wait.
    ah0 = *(const half8*)&sc[lo*72 + quad*8];
    ah1 = *(const half8*)&sc[lo*72 + 32 + quad*8];
    if (!LAST){
      _Float16* hout = (_Float16*)outp;
      #pragma unroll
      for (int k2 = 0; k2 < 2; ++k2){
        int node = (lane >> 3) + 8*k2;
        int cell = (lane & 7)*8;
        half8 hvv = *(const half8*)&sc[node*72 + cell];
        *(half8*)&hout[(size_t)(nb+node)*kTT*kHH + (size_t)t*kHH + cell] = hvv;
      }
    }
  }
  if (LAST){
    float* out = (float*)outp;
    floatx4 a = {0.f,0.f,0.f,0.f};
    a = __builtin_amdgcn_mfma_f32_16x16x32_f16(ah0, FW[0], a, 0,0,0);
    a = __builtin_amdgcn_mfma_f32_16x16x32_f16(ah1, FW[1], a, 0,0,0);
    float bo = fcb[lo];
    #pragma unroll
    for (int r = 0; r < 4; ++r)
      out[(size_t)(nb + quad*4 + r)*kOUT + lo] = a[r] + bo;
  }
}

extern "C" void kernel_launch(void* const* d_in, const int* in_sizes, int n_in,
                              void* d_out, int out_size, void* d_ws, size_t ws_size,
                              hipStream_t stream){
  const float* x    = (const float*)d_in[0];
  const int*   ei   = (const int*)  d_in[1];
  const float* gw0  = (const float*)d_in[2];
  const float* gb0  = (const float*)d_in[3];
  const float* gw1  = (const float*)d_in[4];
  const float* gb1  = (const float*)d_in[5];
  const float* wih0 = (const float*)d_in[6];
  const float* whh0 = (const float*)d_in[7];
  const float* bih0 = (const float*)d_in[8];
  const float* bhh0 = (const float*)d_in[9];
  const float* wih1 = (const float*)d_in[10];
  const float* whh1 = (const float*)d_in[11];
  const float* bih1 = (const float*)d_in[12];
  const float* bhh1 = (const float*)d_in[13];
  const float* fcw  = (const float*)d_in[14];
  const float* fcb  = (const float*)d_in[15];
  float* out = (float*)d_out;

  char* ws = (char*)d_ws;
  size_t p = 0;
  auto carve = [&](size_t bytes)->char*{
    char* r = ws + p;
    p += (bytes + 255) & ~(size_t)255;
    return r;
  };
  int*   anyf = (int*)  carve(256);
  int*   cnt  = (int*)  carve(sizeof(int)*kNN);
  int*   cur  = (int*)  carve(sizeof(int)*kNN);
  size_t zbytes = p;
  int*   offs = (int*)  carve(sizeof(int)*(kNN+1));
  float* dis  = (float*)carve(sizeof(float)*kNN);
  int2*  edat = (int2*) carve(sizeof(int2)*kNE);
  _Float16* xh   = (_Float16*)carve(sizeof(_Float16)*(size_t)kNN*kTT*kFIN);
  _Float16* aggX = (_Float16*)carve(sizeof(_Float16)*(size_t)kNN*kTT*kFIN);
  _Float16* bufA = (_Float16*)carve(sizeof(_Float16)*(size_t)kNN*kTT*kHH);
  _Float16* bufB = (_Float16*)carve(sizeof(_Float16)*(size_t)kNN*kTT*kHH);
  (void)ws_size; (void)in_sizes; (void)n_in; (void)out_size;

  hipMemsetAsync(ws, 0, zbytes, stream);
  k_detect_cast<<<120, 256, 0, stream>>>(ei, anyf, x, xh);
  k_deg    <<<(kNE+255)/256, 256, 0, stream>>>(ei, anyf, cnt);
  k_scan   <<<1, 256, 0, stream>>>(cnt, offs, dis);
  k_scatter<<<(kNE+255)/256, 256, 0, stream>>>(ei, anyf, offs, cur, dis, edat);

  // GCN-0: aggregate 32-feat x first (A_hat x), then GEMM (+gb0+relu), t-major
  k_agg<kFIN><<<(kNN*(kTT/4))/4, 256, 0, stream>>>(xh, aggX, dis, offs, edat);
  k_gemm<kFIN, kHH, false><<<(kNN*kTT)/64, 256, 0, stream>>>(aggX, gw0, gb0, bufB);
  // GCN-1: aggregate 64-feat, GEMM (+gb1+relu) writes node-major for LSTM
  k_agg<kHH><<<(kNN*(kTT/2))/4, 256, 0, stream>>>(bufB, bufA, dis, offs, edat);
  k_gemm<kHH, kHH, true><<<(kNN*kTT)/64, 256, 0, stream>>>(bufA, gw1, gb1, bufB);

  // Barrier-free LSTM: layer 0 -> bufA (fp16 h-seq), layer 1 + FC -> out
  k_lstm<false><<<(kNN/16 + 1)/2, 128, 0, stream>>>(bufB, wih0, whh0, bih0, bhh0,
                                                    nullptr, nullptr, bufA);
  k_lstm<true ><<<(kNN/16 + 1)/2, 128, 0, stream>>>(bufA, wih1, whh1, bih1, bhh1,
                                                    fcw, fcb, out);
}

// Round 11
// 344.653 us; speedup vs baseline: 1.0050x; 1.0050x over previous
//
#include <hip/hip_runtime.h>
#include <hip/hip_bf16.h>

constexpr int kNN  = 10000;   // nodes
constexpr int kTT  = 12;      // timesteps
constexpr int kFIN = 32;      // input features
constexpr int kHH  = 64;      // hidden
constexpr int kH4  = 256;     // 4*hidden (gates)
constexpr int kOUT = 16;      // output features
constexpr int kNE  = 160000;  // edges

typedef _Float16 half8 __attribute__((ext_vector_type(8)));
typedef _Float16 half4 __attribute__((ext_vector_type(4)));
typedef _Float16 half2t __attribute__((ext_vector_type(2)));
typedef float floatx4 __attribute__((ext_vector_type(4)));

__device__ __forceinline__ float sigf(float x){ return 1.f/(1.f+__expf(-x)); }
__device__ __forceinline__ float tanh_fast(float x){
  float xc = fminf(fmaxf(x,-30.f),30.f);
  float e = __expf(-2.f*xc);
  return (1.f-e)/(1.f+e);
}

// int64-vs-int32 edge_index detection (odd words all zero <=> int64) fused
// with the x fp32 -> fp16 cast.
__global__ void k_detect_cast(const int* __restrict__ ei, int* __restrict__ anyf,
                              const float* __restrict__ x, _Float16* __restrict__ xh){
  int a = 0;
  for (int i = blockIdx.x*256 + threadIdx.x; i < kNE; i += gridDim.x*256)
    a |= ei[2*i+1];
  unsigned long long m = __ballot(a != 0);
  if ((threadIdx.x & 63) == 0 && m) atomicOr(anyf, 1);
  const int NV = kNN*kTT*kFIN/4;
  for (int i = blockIdx.x*256 + threadIdx.x; i < NV; i += gridDim.x*256){
    float4 v = *(const float4*)&x[4*i];
    half4 h;
    h[0]=(_Float16)v.x; h[1]=(_Float16)v.y; h[2]=(_Float16)v.z; h[3]=(_Float16)v.w;
    *(half4*)&xh[4*i] = h;
  }
}

__global__ void k_deg(const int* __restrict__ ei, const int* __restrict__ anyf,
                      int* __restrict__ cnt){
  int e = blockIdx.x*256 + threadIdx.x;
  if (e >= kNE) return;
  int c = (anyf[0]==0) ? ei[2*(kNE+e)] : ei[kNE+e];
  atomicAdd(&cnt[c], 1);
}

// Exclusive scan of in-degree (single block) + dis = rsqrt(deg+selfloop)
__global__ void k_scan(const int* __restrict__ cnt, int* __restrict__ offs,
                       float* __restrict__ dis){
  __shared__ int wsum[4];
  int tid = threadIdx.x;
  const int CH = (kNN + 255)/256;
  int lo = tid*CH, hi = min(lo+CH, kNN);
  int s = 0;
  for (int i = lo; i < hi; ++i) s += cnt[i];
  int orig = s;
  int lane = tid & 63, wv = tid >> 6;
  #pragma unroll
  for (int d = 1; d < 64; d <<= 1){
    int v = __shfl_up(s, d, 64);
    if (lane >= d) s += v;
  }
  if (lane == 63) wsum[wv] = s;
  __syncthreads();
  int add = 0;
  for (int k2 = 0; k2 < wv; ++k2) add += wsum[k2];
  int run = s - orig + add;
  for (int i = lo; i < hi; ++i){ offs[i] = run; run += cnt[i]; }
  if (hi == kNN) offs[kNN] = run;
  for (int i = tid; i < kNN; i += 256) dis[i] = rsqrtf((float)(cnt[i]+1));
}

// CSR scatter; packs (src, weight) into one int2 per edge.
__global__ void k_scatter(const int* __restrict__ ei, const int* __restrict__ anyf,
                          const int* __restrict__ offs, int* __restrict__ cur,
                          const float* __restrict__ dis,
                          int2* __restrict__ edat){
  int e = blockIdx.x*256 + threadIdx.x;
  if (e >= kNE) return;
  int f = (anyf[0]==0);
  int r = f ? ei[2*e]         : ei[e];
  int c = f ? ei[2*(kNE+e)]   : ei[kNE+e];
  int p = offs[c] + atomicAdd(&cur[c], 1);
  edat[p] = make_int2(r, __float_as_int(dis[r]*dis[c]));
}

// Pure GCN aggregation (bias/relu folded into the following GEMM).
template<int F>
__global__ __launch_bounds__(256) void k_agg(const _Float16* __restrict__ hin,
                     _Float16* __restrict__ hout,
                     const float* __restrict__ dis,
                     const int* __restrict__ offs, const int2* __restrict__ edat){
  constexpr int LPF = F/2;
  constexpr int TPW = 64/LPF;
  int wid = threadIdx.x >> 6, lane = threadIdx.x & 63;
  int gw = blockIdx.x*4 + wid;
  int tq = gw / kNN, n = gw - tq*kNN;
  int fp = lane & (LPF-1), tsub = lane / LPF;
  int t = TPW*tq + tsub;
  const _Float16* hb = hin + (size_t)t*kNN*F;
  float d = dis[n], ws = d*d;
  half2t sv = *(const half2t*)&hb[(size_t)n*F + 2*fp];
  float a0 = ws*(float)sv[0], a1 = ws*(float)sv[1];
  int e0 = __builtin_amdgcn_readfirstlane(offs[n]);
  int e1 = __builtin_amdgcn_readfirstlane(offs[n+1]);
  int e = e0;
  for (; e + 8 <= e1; e += 8){
    int2 d8[8];
    #pragma unroll
    for (int u = 0; u < 8; ++u) d8[u] = edat[e+u];
    half2t v[8];
    #pragma unroll
    for (int u = 0; u < 8; ++u) v[u] = *(const half2t*)&hb[(size_t)d8[u].x*F + 2*fp];
    #pragma unroll
    for (int u = 0; u < 8; ++u){
      float wu = __int_as_float(d8[u].y);
      a0 = fmaf(wu, (float)v[u][0], a0);
      a1 = fmaf(wu, (float)v[u][1], a1);
    }
  }
  for (; e < e1; ++e){
    int2 du = edat[e];
    float wu = __int_as_float(du.y);
    half2t vu = *(const half2t*)&hb[(size_t)du.x*F + 2*fp];
    a0 = fmaf(wu, (float)vu[0], a0);
    a1 = fmaf(wu, (float)vu[1], a1);
  }
  half2t o; o[0] = (_Float16)a0; o[1] = (_Float16)a1;
  *(half2t*)&hout[((size_t)t*kNN + n)*F + 2*fp] = o;
}

// Tiled GEMM: out[M,N] = relu(in[M,K] @ W[K,N] + bias), fp16 in/out, fp32 acc.
template<int K, int N, bool NM>
__global__ __launch_bounds__(256) void k_gemm(const _Float16* __restrict__ in,
                      const float* __restrict__ Wg, const float* __restrict__ bias,
                      _Float16* __restrict__ out){
  constexpr int COLG = N/4;
  constexpr int ROWG = 256/COLG;
  constexpr int MR   = 4;
  constexpr int MTILE= ROWG*MR;
  constexpr int AP   = K + 4;
  __shared__ float Wl[K*N];
  __shared__ float Al[MTILE*AP];
  int tid = threadIdx.x;
  int m0 = blockIdx.x*MTILE;
  for (int idx = tid; idx < MTILE*K/8; idx += 256){
    int r = idx/(K/8), k8 = idx - r*(K/8);
    half8 v = *(const half8*)&in[(size_t)(m0 + r)*K + k8*8];
    float* dst = &Al[r*AP + k8*8];
    #pragma unroll
    for (int j = 0; j < 8; ++j) dst[j] = (float)v[j];
  }
  for (int idx = tid; idx < K*N; idx += 256) Wl[idx] = Wg[idx];
  __syncthreads();
  int cg = tid % COLG, rg = tid / COLG;
  int c0 = cg*4, r0 = rg*MR;
  float acc[MR][4];
  #pragma unroll
  for (int r=0;r<MR;++r){acc[r][0]=0.f;acc[r][1]=0.f;acc[r][2]=0.f;acc[r][3]=0.f;}
  #pragma unroll 2
  for (int k = 0; k < K; k += 4){
    float4 wv[4];
    #pragma unroll
    for (int kk = 0; kk < 4; ++kk) wv[kk] = *(const float4*)&Wl[(k+kk)*N + c0];
    #pragma unroll
    for (int r = 0; r < MR; ++r){
      float4 a4 = *(const float4*)&Al[(r0+r)*AP + k];
      acc[r][0] = fmaf(a4.x, wv[0].x, acc[r][0]);
      acc[r][1] = fmaf(a4.x, wv[0].y, acc[r][1]);
      acc[r][2] = fmaf(a4.x, wv[0].z, acc[r][2]);
      acc[r][3] = fmaf(a4.x, wv[0].w, acc[r][3]);
      acc[r][0] = fmaf(a4.y, wv[1].x, acc[r][0]);
      acc[r][1] = fmaf(a4.y, wv[1].y, acc[r][1]);
      acc[r][2] = fmaf(a4.y, wv[1].z, acc[r][2]);
      acc[r][3] = fmaf(a4.y, wv[1].w, acc[r][3]);
      acc[r][0] = fmaf(a4.z, wv[2].x, acc[r][0]);
      acc[r][1] = fmaf(a4.z, wv[2].y, acc[r][1]);
      acc[r][2] = fmaf(a4.z, wv[2].z, acc[r][2]);
      acc[r][3] = fmaf(a4.z, wv[2].w, acc[r][3]);
      acc[r][0] = fmaf(a4.w, wv[3].x, acc[r][0]);
      acc[r][1] = fmaf(a4.w, wv[3].y, acc[r][1]);
      acc[r][2] = fmaf(a4.w, wv[3].z, acc[r][2]);
      acc[r][3] = fmaf(a4.w, wv[3].w, acc[r][3]);
    }
  }
  float4 bb = *(const float4*)&bias[c0];
  #pragma unroll
  for (int r = 0; r < MR; ++r){
    half4 hv;
    hv[0]=(_Float16)fmaxf(acc[r][0]+bb.x, 0.f);
    hv[1]=(_Float16)fmaxf(acc[r][1]+bb.y, 0.f);
    hv[2]=(_Float16)fmaxf(acc[r][2]+bb.z, 0.f);
    hv[3]=(_Float16)fmaxf(acc[r][3]+bb.w, 0.f);
    int m = m0 + r0 + r;
    size_t oi;
    if (NM){ int t = m/kNN, n = m - t*kNN; oi = ((size_t)n*kTT + t)*N + c0; }
    else    oi = (size_t)m*N + c0;
    *(half4*)&out[oi] = hv;
  }
}

// Stage a (256,64) fp32 matrix into LDS as fp16 MFMA B-fragments:
// frag fi=(g*2+kt): lane ln's half8 at dst[(fi*64+ln)*8] = W[g*16+(ln&15)]
// [kt*32+(ln>>4)*8 + j]  -> in-kernel read is one ds_read_b128 per frag.
__device__ __forceinline__ void stage_frags(const float* __restrict__ W,
                                            _Float16* __restrict__ dst,
                                            int tid, int nthr){
  for (int idx = tid; idx < 2048; idx += nthr){
    int fi = idx >> 6, ln = idx & 63;
    int g = fi >> 1, kt = fi & 1;
    const float* s = W + (size_t)(g*16 + (ln & 15))*kHH + kt*32 + ((ln >> 4) << 3);
    half8 v;
    #pragma unroll
    for (int j = 0; j < 8; ++j) v[j] = (_Float16)s[j];
    *(half8*)&dst[(size_t)idx*8] = v;
  }
}

// Barrier-free LSTM layer: ONE WAVE owns a 16-node tile end-to-end; the
// 12-step recurrence has ZERO __syncthreads (h C->A transform via wave-
// private LDS scratch; same-wave DS ops are in-order).
// R10 post-mortem: no spill traffic existed (WRITE_SIZE == hout exactly) —
// the ~12k cyc/t invariant across R4-R10 is attributed to I-CACHE THRASH:
// the fully-unrolled t-loop emitted ~60-70KB of straight-line code vs the
// 32KB I-cache, and at ~0.5 waves/SIMD every line is a ~200cyc L2 fetch,
// re-missed every iteration. Fix: `#pragma unroll 1` on the t-loop (body
// emitted once, ~8KB, I-cache resident). To keep the rolled body register-
// friendly, Wih fragments live in a second persistent 32KB LDS image
// (symmetric with Whh) instead of a 128-VGPR array; gg/q/r stay unrolled
// so cst/acc keep static indices.
// MFMA 16x16x32 layouts: A[m=lane&15][k=(lane>>4)*8+j], B^T rows same,
// C/D[row=(lane>>4)*4+r][col=lane&15]. acc[q][r] = gate q of
// (node=quad*4+r, cell=gg*16+lo); bias broadcast per (q,cell) across r;
// h scratch store sc[(quad*4+r)*72 + gg*16+lo] (per-r b16 scatter).
// LAST: fuse FC on h(t=11) (2 MFMAs), write fp32 out; else write fp16 h-seq.
template<bool LAST>
__global__ __launch_bounds__(128, 1) void k_lstm(const _Float16* __restrict__ xin,
                     const float* __restrict__ wih, const float* __restrict__ whh,
                     const float* __restrict__ bih, const float* __restrict__ bhh,
                     const float* __restrict__ fcw, const float* __restrict__ fcb,
                     void* __restrict__ outp){
  __shared__ _Float16 WI[16384];     // 32KB Wih fragment image (persistent)
  __shared__ _Float16 WH[16384];     // 32KB Whh fragment image (persistent)
  __shared__ float    biasL[kH4];    // 1KB summed bias
  __shared__ _Float16 hs[2][1152];   // per-wave h scratch: [node*72 + cell]
  int tid = threadIdx.x, w = tid >> 6, lane = tid & 63;
  int lo = lane & 15, quad = lane >> 4;
  int tile = blockIdx.x*2 + w;
  int nb = tile*16;

  // --- one-time preload (the only barrier in the kernel) ---
  stage_frags(wih, WI, tid, 128);
  stage_frags(whh, WH, tid, 128);
  for (int i = tid; i < kH4; i += 128) biasL[i] = bih[i] + bhh[i];
  __syncthreads();
  if (tile >= kNN/16) return;        // after the barrier

  // Per-lane bias: gate q, cell gg*16+lo (constant across the 4 node-rows r)
  float bias_v[4][4];
  #pragma unroll
  for (int gg = 0; gg < 4; ++gg)
    #pragma unroll
    for (int q = 0; q < 4; ++q)
      bias_v[gg][q] = biasL[q*64 + gg*16 + lo];

  half8 FW[2];
  if (LAST){
    #pragma unroll
    for (int kt = 0; kt < 2; ++kt){
      const float* pf = fcw + (size_t)lo*kHH + kt*32 + quad*8;
      half8 f;
      #pragma unroll
      for (int j = 0; j < 8; ++j) f[j] = (_Float16)pf[j];
      FW[kt] = f;
    }
  }

  const _Float16* xr = xin + (size_t)(nb + lo)*kTT*kHH;
  _Float16* sc = &hs[w][0];
  floatx4 cst[4];
  #pragma unroll
  for (int gg = 0; gg < 4; ++gg) cst[gg] = (floatx4){0.f,0.f,0.f,0.f};
  half8 ah0, ah1;
  half8 axn0 = *(const half8*)&xr[quad*8];
  half8 axn1 = *(const half8*)&xr[32 + quad*8];

  #pragma unroll 1
  for (int t = 0; t < kTT; ++t){
    half8 ax0 = axn0, ax1 = axn1;
    if (t < kTT-1){
      axn0 = *(const half8*)&xr[(size_t)(t+1)*kHH + quad*8];
      axn1 = *(const half8*)&xr[(size_t)(t+1)*kHH + 32 + quad*8];
    }
    #pragma unroll
    for (int gg = 0; gg < 4; ++gg){
      floatx4 acc[4];
      #pragma unroll
      for (int q = 0; q < 4; ++q){
        float b = bias_v[gg][q];
        acc[q] = (floatx4){b, b, b, b};
      }
      #pragma unroll
      for (int q = 0; q < 4; ++q){
        int ga = q*4 + gg;
        half8 wi0 = *(const half8*)&WI[(size_t)((ga*2+0)*64 + lane)*8];
        half8 wi1 = *(const half8*)&WI[(size_t)((ga*2+1)*64 + lane)*8];
        acc[q] = __builtin_amdgcn_mfma_f32_16x16x32_f16(ax0, wi0, acc[q], 0,0,0);
        acc[q] = __builtin_amdgcn_mfma_f32_16x16x32_f16(ax1, wi1, acc[q], 0,0,0);
      }
      if (t > 0){
        #pragma unroll
        for (int q = 0; q < 4; ++q){
          int ga = q*4 + gg;
          half8 w0 = *(const half8*)&WH[(size_t)((ga*2+0)*64 + lane)*8];
          half8 w1 = *(const half8*)&WH[(size_t)((ga*2+1)*64 + lane)*8];
          acc[q] = __builtin_amdgcn_mfma_f32_16x16x32_f16(ah0, w0, acc[q], 0,0,0);
          acc[q] = __builtin_amdgcn_mfma_f32_16x16x32_f16(ah1, w1, acc[q], 0,0,0);
        }
      }
      #pragma unroll
      for (int r = 0; r < 4; ++r){
        float ii = sigf(acc[0][r]);
        float ff = sigf(acc[1][r]);
        float gt = tanh_fast(acc[2][r]);
        float oo = sigf(acc[3][r]);
        float cc = ff*cst[gg][r] + ii*gt;
        cst[gg][r] = cc;
        float hv = oo * tanh_fast(cc);
        // value is (node=quad*4+r, cell=gg*16+lo): scatter b16 per r
        sc[(quad*4 + r)*72 + gg*16 + lo] = (_Float16)hv;
      }
    }
    // h(t) C-layout -> A-layout for t+1 (and the FC at t=11). Same-wave DS
    // ops are in-order; compiler inserts the lgkmcnt wait.
    ah0 = *(const half8*)&sc[lo*72 + quad*8];
    ah1 = *(const half8*)&sc[lo*72 + 32 + quad*8];
    if (!LAST){
      _Float16* hout = (_Float16*)outp;
      #pragma unroll
      for (int k2 = 0; k2 < 2; ++k2){
        int node = (lane >> 3) + 8*k2;
        int cell = (lane & 7)*8;
        half8 hvv = *(const half8*)&sc[node*72 + cell];
        *(half8*)&hout[(size_t)(nb+node)*kTT*kHH + (size_t)t*kHH + cell] = hvv;
      }
    }
  }
  if (LAST){
    float* out = (float*)outp;
    floatx4 a = {0.f,0.f,0.f,0.f};
    a = __builtin_amdgcn_mfma_f32_16x16x32_f16(ah0, FW[0], a, 0,0,0);
    a = __builtin_amdgcn_mfma_f32_16x16x32_f16(ah1, FW[1], a, 0,0,0);
    float bo = fcb[lo];
    #pragma unroll
    for (int r = 0; r < 4; ++r)
      out[(size_t)(nb + quad*4 + r)*kOUT + lo] = a[r] + bo;
  }
}

extern "C" void kernel_launch(void* const* d_in, const int* in_sizes, int n_in,
                              void* d_out, int out_size, void* d_ws, size_t ws_size,
                              hipStream_t stream){
  const float* x    = (const float*)d_in[0];
  const int*   ei   = (const int*)  d_in[1];
  const float* gw0  = (const float*)d_in[2];
  const float* gb0  = (const float*)d_in[3];
  const float* gw1  = (const float*)d_in[4];
  const float* gb1  = (const float*)d_in[5];
  const float* wih0 = (const float*)d_in[6];
  const float* whh0 = (const float*)d_in[7];
  const float* bih0 = (const float*)d_in[8];
  const float* bhh0 = (const float*)d_in[9];
  const float* wih1 = (const float*)d_in[10];
  const float* whh1 = (const float*)d_in[11];
  const float* bih1 = (const float*)d_in[12];
  const float* bhh1 = (const float*)d_in[13];
  const float* fcw  = (const float*)d_in[14];
  const float* fcb  = (const float*)d_in[15];
  float* out = (float*)d_out;

  char* ws = (char*)d_ws;
  size_t p = 0;
  auto carve = [&](size_t bytes)->char*{
    char* r = ws + p;
    p += (bytes + 255) & ~(size_t)255;
    return r;
  };
  int*   anyf = (int*)  carve(256);
  int*   cnt  = (int*)  carve(sizeof(int)*kNN);
  int*   cur  = (int*)  carve(sizeof(int)*kNN);
  size_t zbytes = p;
  int*   offs = (int*)  carve(sizeof(int)*(kNN+1));
  float* dis  = (float*)carve(sizeof(float)*kNN);
  int2*  edat = (int2*) carve(sizeof(int2)*kNE);
  _Float16* xh   = (_Float16*)carve(sizeof(_Float16)*(size_t)kNN*kTT*kFIN);
  _Float16* aggX = (_Float16*)carve(sizeof(_Float16)*(size_t)kNN*kTT*kFIN);
  _Float16* bufA = (_Float16*)carve(sizeof(_Float16)*(size_t)kNN*kTT*kHH);
  _Float16* bufB = (_Float16*)carve(sizeof(_Float16)*(size_t)kNN*kTT*kHH);
  (void)ws_size; (void)in_sizes; (void)n_in; (void)out_size;

  hipMemsetAsync(ws, 0, zbytes, stream);
  k_detect_cast<<<120, 256, 0, stream>>>(ei, anyf, x, xh);
  k_deg    <<<(kNE+255)/256, 256, 0, stream>>>(ei, anyf, cnt);
  k_scan   <<<1, 256, 0, stream>>>(cnt, offs, dis);
  k_scatter<<<(kNE+255)/256, 256, 0, stream>>>(ei, anyf, offs, cur, dis, edat);

  // GCN-0: aggregate 32-feat x first (A_hat x), then GEMM (+gb0+relu), t-major
  k_agg<kFIN><<<(kNN*(kTT/4))/4, 256, 0, stream>>>(xh, aggX, dis, offs, edat);
  k_gemm<kFIN, kHH, false><<<(kNN*kTT)/64, 256, 0, stream>>>(aggX, gw0, gb0, bufB);
  // GCN-1: aggregate 64-feat, GEMM (+gb1+relu) writes node-major for LSTM
  k_agg<kHH><<<(kNN*(kTT/2))/4, 256, 0, stream>>>(bufB, bufA, dis, offs, edat);
  k_gemm<kHH, kHH, true><<<(kNN*kTT)/64, 256, 0, stream>>>(bufA, gw1, gb1, bufB);

  // Barrier-free LSTM: layer 0 -> bufA (fp16 h-seq), layer 1 + FC -> out
  k_lstm<false><<<(kNN/16 + 1)/2, 128, 0, stream>>>(bufB, wih0, whh0, bih0, bhh0,
                                                    nullptr, nullptr, bufA);
  k_lstm<true ><<<(kNN/16 + 1)/2, 128, 0, stream>>>(bufA, wih1, whh1, bih1, bhh1,
                                                    fcw, fcb, out);
}